// Round 8
// baseline (494.545 us; speedup 1.0000x reference)
//
#include <hip/hip_runtime.h>

// out[b, I[e]] += inputs[b, J[e]] * W3[e] * velocity[J[e]]; out += bias
// R2: per-edge global atomics = 204.8MB atomic-path traffic (bound).
// R4: bucket build + gather -> 161.7us; build WRITE 47MB = 1 line per 8B rec.
// R5: nt stores FALSIFIED (WRITE rose; nt = no-allocate partial-line writes).
// R6: 2-pass counting sort, dense writes -> 157.1us; harness ws-poison fill
//     (47us) is fixed overhead; all my kernels < 47us each.
// R7: fused hist into k_prep -> RACE (zero and atomicAdd of coarse_hist in
//     the same dispatch; block order undefined) -> tripwire divergence.
// R8: R7 structure, but coarse_hist zeroed by stream-ordered hipMemsetAsync
//     BEFORE k_prep. 1 block per 256-row bucket gather with LDS atomicAdd
//     (ds_add_f32, 65-stride tile = conflict-free), part[] consumed directly.

#define BATCH 64
#define ROWS_PC 256           // rows per coarse bucket
#define PCHUNK 4096           // edges per partition block

typedef unsigned long long ull;

// ---- K1: transpose inputs [B,N] -> in_T [N,B]; accumulate coarse histogram ----
// coarse_hist must be zeroed by a PRIOR dispatch (memset) - same-dispatch
// zeroing raced in R7.
__global__ void k_prep(const float* __restrict__ in, float* __restrict__ in_T,
                       const int* __restrict__ I, int* __restrict__ coarse_hist,
                       int NC, int N, int E, int echunk) {
    const int t = threadIdx.x;
    __shared__ float tile[64 * 65];
    __shared__ int h[256];
    h[t] = 0;

    const int n0 = blockIdx.x * 64;
    const int x  = t & 63;
    const int r  = t >> 6;
    for (int b = r; b < BATCH; b += 4) {
        float v = 0.f;
        if (n0 + x < N) v = in[(size_t)b * N + n0 + x];
        tile[x * 65 + b] = v;
    }
    __syncthreads();
    for (int xr = r; xr < 64; xr += 4) {
        if (n0 + xr < N) in_T[(size_t)(n0 + xr) * BATCH + x] = tile[xr * 65 + x];
    }

    // histogram this block's edge chunk (LDS-aggregated)
    const int e0 = blockIdx.x * echunk;
    int e1 = e0 + echunk; if (e1 > E) e1 = E;
    for (int e = e0 + t; e < e1; e += 256) atomicAdd(&h[I[e] >> 8], 1);
    __syncthreads();
    if (t < NC && h[t]) atomicAdd(&coarse_hist[t], h[t]);
}

// ---- K2: exclusive scan of NC (<=256) coarse counts; init cursors ----
__global__ void k_scan(const int* __restrict__ coarse_hist, int* __restrict__ coarse_base,
                       int* __restrict__ gcursor, int NC) {
    __shared__ int sh[256];
    const int t = threadIdx.x;
    const int v = (t < NC) ? coarse_hist[t] : 0;
    sh[t] = v;
    __syncthreads();
    for (int off = 1; off < 256; off <<= 1) {
        const int u = (t >= off) ? sh[t - off] : 0;
        __syncthreads();
        sh[t] += u;
        __syncthreads();
    }
    if (t < NC) { coarse_base[t] = sh[t] - v; gcursor[t] = sh[t] - v; }
    if (t == NC - 1) coarse_base[NC] = sh[t];   // = E
}

// ---- K3: partition into coarse buckets (dense run reservations) ----
// record u64: hi32 = bits(w), lo32 = (i & 255) << 16 | j
__global__ void k_partition(const int* __restrict__ I, const int* __restrict__ J,
                            const float* __restrict__ W3, const float* __restrict__ velocity,
                            int* __restrict__ gcursor, ull* __restrict__ part, int E) {
    __shared__ int hist[256];
    __shared__ int base[256];
    const int t = threadIdx.x;
    hist[t] = 0;
    __syncthreads();
    const int e0 = blockIdx.x * PCHUNK;
    int e1 = e0 + PCHUNK; if (e1 > E) e1 = E;
    for (int e = e0 + t; e < e1; e += 256) atomicAdd(&hist[I[e] >> 8], 1);
    __syncthreads();
    const int cnt = hist[t];
    base[t] = cnt ? atomicAdd(&gcursor[t], cnt) : 0;   // one reservation per (block,bucket)
    __syncthreads();
    hist[t] = 0;                                        // reuse as rank counters
    __syncthreads();
    for (int e = e0 + t; e < e1; e += 256) {
        const int   i = I[e];
        const int   j = J[e];
        const float w = W3[e] * velocity[j];
        const int   c = i >> 8;
        const int   r = atomicAdd(&hist[c], 1);
        const unsigned lo = ((unsigned)(i & 255) << 16) | (unsigned)j;
        part[(size_t)base[c] + r] = ((ull)__float_as_uint(w) << 32) | lo;
    }
}

// ---- K4: gather. 1 block = 1 coarse bucket = 256 rows. 1024 thr = 16 waves
// all streaming the bucket window, accumulating via LDS atomicAdd. ----
__global__ void __launch_bounds__(1024) k_gather(
        const float* __restrict__ in_T, const ull* __restrict__ part,
        const int* __restrict__ coarse_base, const float* __restrict__ bias,
        float* __restrict__ out, int N) {
    __shared__ float tile[ROWS_PC * 65];
    const int t    = threadIdx.x;
    const int lane = t & 63;
    const int w    = t >> 6;                 // wave 0..15

    for (int idx = t; idx < ROWS_PC * 65; idx += 1024) tile[idx] = 0.f;
    __syncthreads();

    const int beg = coarse_base[blockIdx.x];
    const int end = coarse_base[blockIdx.x + 1];

    for (int base = beg + w * 64; base < end; base += 16 * 64) {
        int cc = end - base; if (cc > 64) cc = 64;
        ull rec = 0ull;                          // pad -> harmless +0 to row0
        if (lane < cc) rec = part[base + lane];
        const int rlo = (int)(unsigned)(rec & 0xffffffffu);
        const int rhi = (int)(unsigned)(rec >> 32);
        for (int k0 = 0; k0 < cc; k0 += 8) {
            float v[8], ww[8]; int li[8];
            #pragma unroll
            for (int u = 0; u < 8; ++u) {
                const int k = k0 + u;
                const unsigned ij = (unsigned)__shfl(rlo, k);
                ww[u] = __uint_as_float((unsigned)__shfl(rhi, k));
                li[u] = (int)((ij >> 16) & 255);     // row within bucket
                const int j = (int)(ij & 0xffffu);
                v[u] = in_T[j * BATCH + lane];       // 8 independent loads in flight
            }
            #pragma unroll
            for (int u = 0; u < 8; ++u) {
                atomicAdd(&tile[li[u] * 65 + lane], v[u] * ww[u]);  // ds_add_f32
            }
        }
    }
    __syncthreads();

    // epilogue: rows [n0, n0+256) -> out[b*N+n] + bias, coalesced over c
    const int n0 = blockIdx.x * ROWS_PC;
    const int c  = t & 255;
    const int bq = t >> 8;                   // 0..3
    const int n = n0 + c;
    if (n < N) {
        const float bv = bias[n];
        for (int b = bq; b < BATCH; b += 4)
            out[(size_t)b * N + n] = tile[c * 65 + b] + bv;
    }
}

// ---- fallback path (ws too small or N doesn't fit u16): direct atomics ----
__global__ void k_edge_scatter_direct(const float* __restrict__ in,
                                      const float* __restrict__ W3,
                                      const float* __restrict__ velocity,
                                      const int* __restrict__ I,
                                      const int* __restrict__ J,
                                      float* __restrict__ out, int N, int E) {
    const int lane = threadIdx.x & 63;
    const long wave   = (long)blockIdx.x * (blockDim.x >> 6) + (threadIdx.x >> 6);
    const long nwaves = (long)gridDim.x * (blockDim.x >> 6);
    for (long base = wave * 64; base < E; base += nwaves * 64) {
        const long e = base + lane;
        int iv = 0, jv = 0; float wvv = 0.f;
        if (e < E) { iv = I[e]; jv = J[e]; wvv = W3[e] * velocity[jv]; }
        const int cnt = (int)((E - base) < 64 ? (E - base) : 64);
        for (int k = 0; k < cnt; ++k) {
            const int   ii = __shfl(iv, k);
            const int   jj = __shfl(jv, k);
            const float wvx = __shfl(wvv, k);
            const float val = in[(size_t)lane * N + jj] * wvx;
            atomicAdd(&out[(size_t)lane * N + ii], val);
        }
    }
}

__global__ void k_add_bias(const float* __restrict__ bias, float* __restrict__ out, int N, int total) {
    int idx = blockIdx.x * blockDim.x + threadIdx.x;
    if (idx < total) out[idx] += bias[idx % N];
}

extern "C" void kernel_launch(void* const* d_in, const int* in_sizes, int n_in,
                              void* d_out, int out_size, void* d_ws, size_t ws_size,
                              hipStream_t stream) {
    const float* inputs   = (const float*)d_in[0];
    const float* W3       = (const float*)d_in[1];
    const float* bias     = (const float*)d_in[2];
    const float* velocity = (const float*)d_in[3];
    const int*   I        = (const int*)d_in[4];
    const int*   J        = (const int*)d_in[5];
    const int E = in_sizes[1];
    const int N = in_sizes[3];
    float* out = (float*)d_out;

    const size_t mat_elems = (size_t)N * BATCH;
    const int NC   = (N + ROWS_PC - 1) / ROWS_PC;   // coarse buckets
    const int nb_n = (N + 63) / 64;
    const int nb_e = (E + PCHUNK - 1) / PCHUNK;
    const int echunk = (E + nb_n - 1) / nb_n;       // edges histogrammed per prep block

    // ws: in_T | part | coarse_hist | coarse_base | gcursor
    const size_t need = mat_elems * sizeof(float)
                      + (size_t)E * sizeof(ull)
                      + (size_t)(NC + (NC + 1) + NC) * sizeof(int);

    if (ws_size >= need && N <= 65535 && NC <= 256) {
        float* in_T        = (float*)d_ws;
        ull*   part        = (ull*)(in_T + mat_elems);
        int*   coarse_hist = (int*)(part + E);
        int*   coarse_base = coarse_hist + NC;
        int*   gcursor     = coarse_base + NC + 1;

        // stream-ordered zero BEFORE k_prep (same-dispatch zeroing raced in R7)
        hipMemsetAsync(coarse_hist, 0, (size_t)NC * sizeof(int), stream);
        k_prep     <<<nb_n, 256,  0, stream>>>(inputs, in_T, I, coarse_hist, NC, N, E, echunk);
        k_scan     <<<1,    256,  0, stream>>>(coarse_hist, coarse_base, gcursor, NC);
        k_partition<<<nb_e, 256,  0, stream>>>(I, J, W3, velocity, gcursor, part, E);
        k_gather   <<<NC,   1024, 0, stream>>>(in_T, part, coarse_base, bias, out, N);
    } else {
        hipMemsetAsync(out, 0, (size_t)out_size * sizeof(float), stream);
        const int waves_needed   = (E + 63) / 64;
        const int scatter_blocks = (waves_needed + 3) / 4;
        k_edge_scatter_direct<<<scatter_blocks, 256, 0, stream>>>(inputs, W3, velocity, I, J, out, N, E);
        k_add_bias<<<(out_size + 255) / 256, 256, 0, stream>>>(bias, out, N, out_size);
    }
}

// Round 9
// 263.409 us; speedup vs baseline: 1.8775x; 1.8775x over previous
//
#include <hip/hip_runtime.h>

// out[b, I[e]] += inputs[b, J[e]] * W3[e] * velocity[J[e]]; out += bias
// R2: per-edge global atomics = 204.8MB atomic-path traffic (bound).
// R4: bucket build + gather -> 161.7us; build WRITE 47MB = 1 line per 8B rec.
// R5: nt stores FALSIFIED (WRITE rose; nt = no-allocate partial-line writes).
// R6: 2-pass counting sort (coarse partition + finesort), dense writes ->
//     157.1us; all kernels < 47us; harness ws-poison fill (47us) is fixed.
// R7: hist fused with same-dispatch zeroing -> RACE -> tripwire.
// R8: 256-row gather w/ LDS atomics, 196 blocks -> 382us gather (VALU 2.6%,
//     occ 34%: LDS-atomic serialization + starved grid). Lesson: gather needs
//     wave-exclusive rows (plain LDS RMW) and >=800 blocks.
// R9: single-pass partition at 16-row granularity (3125 bins, 12.5KB LDS
//     hists) -> part[] directly gatherable: block = 4 waves x 16-row seg =
//     64 rows, 782 blocks, R6-style 8-wide ILP + plain LDS RMW. Finesort
//     deleted. Hist = direct global atomics fused in prep (memset first).

#define BATCH 64
#define SEG_ROWS 16           // rows per segment (= per gather wave)
#define MAX_NSEG 4096         // static LDS sizing in partition
#define PCHUNK 16384          // edges per partition block

typedef unsigned long long ull;

// ---- K1: transpose inputs [B,N] -> in_T [N,B]; fine histogram (global atomics)
// fine_hist zeroed by PRIOR memset dispatch (R7 lesson: no same-dispatch zero).
__global__ void k_prep(const float* __restrict__ in, float* __restrict__ in_T,
                       const int* __restrict__ I, int* __restrict__ fine_hist,
                       int N, int E, int echunk) {
    const int t = threadIdx.x;
    __shared__ float tile[64 * 65];

    const int n0 = blockIdx.x * 64;
    const int x  = t & 63;
    const int r  = t >> 6;
    for (int b = r; b < BATCH; b += 4) {
        float v = 0.f;
        if (n0 + x < N) v = in[(size_t)b * N + n0 + x];
        tile[x * 65 + b] = v;
    }
    __syncthreads();
    for (int xr = r; xr < 64; xr += 4) {
        if (n0 + xr < N) in_T[(size_t)(n0 + xr) * BATCH + x] = tile[xr * 65 + x];
    }

    // histogram this block's edge chunk: ~256 edges/bin avg -> good atomic
    // locality; 800K total int atomics ~ 3us at measured fabric atomic rate.
    const int e0 = blockIdx.x * echunk;
    int e1 = e0 + echunk; if (e1 > E) e1 = E;
    for (int e = e0 + t; e < e1; e += 256) atomicAdd(&fine_hist[I[e] >> 4], 1);
}

// ---- K2: exclusive scan of nseg (<=4096) counts; init seg_base + gcursor ----
__global__ void __launch_bounds__(1024) k_scan(
        const int* __restrict__ fine_hist, int* __restrict__ seg_base,
        int* __restrict__ gcursor, int nseg) {
    __shared__ int sums[1024];
    const int t = threadIdx.x;
    const int i0 = t * 4;
    int v0 = (i0 + 0 < nseg) ? fine_hist[i0 + 0] : 0;
    int v1 = (i0 + 1 < nseg) ? fine_hist[i0 + 1] : 0;
    int v2 = (i0 + 2 < nseg) ? fine_hist[i0 + 2] : 0;
    int v3 = (i0 + 3 < nseg) ? fine_hist[i0 + 3] : 0;
    const int s = v0 + v1 + v2 + v3;
    sums[t] = s;
    __syncthreads();
    for (int off = 1; off < 1024; off <<= 1) {
        const int u = (t >= off) ? sums[t - off] : 0;
        __syncthreads();
        sums[t] += u;
        __syncthreads();
    }
    int run = sums[t] - s;                       // exclusive prefix
    if (i0 + 0 < nseg) { seg_base[i0 + 0] = run; gcursor[i0 + 0] = run; run += v0; }
    if (i0 + 1 < nseg) { seg_base[i0 + 1] = run; gcursor[i0 + 1] = run; run += v1; }
    if (i0 + 2 < nseg) { seg_base[i0 + 2] = run; gcursor[i0 + 2] = run; run += v2; }
    if (i0 + 3 < nseg) { seg_base[i0 + 3] = run; gcursor[i0 + 3] = run; run += v3; }
    if (t == 1023) seg_base[nseg] = sums[1023];  // = E
}

// ---- K3: partition into 16-row segments (dense run reservations) ----
// record u64: hi32 = bits(w), lo32 = (i & 15) << 16 | j
__global__ void k_partition(const int* __restrict__ I, const int* __restrict__ J,
                            const float* __restrict__ W3, const float* __restrict__ velocity,
                            int* __restrict__ gcursor, ull* __restrict__ part,
                            int nseg, int E) {
    __shared__ int hist[MAX_NSEG];
    __shared__ int hbase[MAX_NSEG];
    const int t = threadIdx.x;
    for (int s = t; s < nseg; s += 256) hist[s] = 0;
    __syncthreads();
    const int e0 = blockIdx.x * PCHUNK;
    int e1 = e0 + PCHUNK; if (e1 > E) e1 = E;
    for (int e = e0 + t; e < e1; e += 256) atomicAdd(&hist[I[e] >> 4], 1);
    __syncthreads();
    for (int s = t; s < nseg; s += 256) {
        const int c = hist[s];
        hbase[s] = c ? atomicAdd(&gcursor[s], c) : 0;  // one reservation per (block,seg)
    }
    __syncthreads();
    for (int s = t; s < nseg; s += 256) hist[s] = 0;   // reuse as rank counters
    __syncthreads();
    for (int e = e0 + t; e < e1; e += 256) {
        const int   i = I[e];
        const int   j = J[e];
        const float w = W3[e] * velocity[j];
        const int   s = i >> 4;
        const int   r = atomicAdd(&hist[s], 1);
        const unsigned lo = ((unsigned)(i & 15) << 16) | (unsigned)j;
        part[(size_t)hbase[s] + r] = ((ull)__float_as_uint(w) << 32) | lo;
    }
}

// ---- K4: gather. Block = 4 waves; wave = one 16-row segment (exclusive).
// 8-wide batched shfl->load (8 loads in flight), plain LDS RMW (no atomics),
// fused bias + transposed store. 782 blocks. ----
__global__ void __launch_bounds__(256) k_gather(
        const float* __restrict__ in_T, const ull* __restrict__ part,
        const int* __restrict__ seg_base, const float* __restrict__ bias,
        float* __restrict__ out, int nseg, int N) {
    __shared__ float tile[64 * 65];             // 64 rows = 4 waves x 16
    const int t    = threadIdx.x;
    const int lane = t & 63;
    const int w    = t >> 6;                    // wave 0..3
    const int seg  = blockIdx.x * 4 + w;

    for (int idx = t; idx < 64 * 65; idx += 256) tile[idx] = 0.f;
    __syncthreads();

    if (seg < nseg) {
        const int wrow0 = w * 16;               // this wave's first local row
        const int beg = seg_base[seg];
        const int end = seg_base[seg + 1];

        for (int base = beg; base < end; base += 64) {
            int cc = end - base; if (cc > 64) cc = 64;
            ull rec = 0ull;                     // pad -> w=0, adds 0 to wave's row0
            if (lane < cc) rec = part[base + lane];
            const int rlo = (int)(unsigned)(rec & 0xffffffffu);
            const int rhi = (int)(unsigned)(rec >> 32);
            for (int k0 = 0; k0 < cc; k0 += 8) {
                float v[8], ww[8]; int li[8];
                #pragma unroll
                for (int u = 0; u < 8; ++u) {
                    const int k = k0 + u;
                    const unsigned ij = (unsigned)__shfl(rlo, k);
                    ww[u] = __uint_as_float((unsigned)__shfl(rhi, k));
                    li[u] = (int)((ij >> 16) & 15);   // row within segment
                    const int j = (int)(ij & 0xffffu);
                    v[u] = in_T[j * BATCH + lane];    // 8 independent loads in flight
                }
                #pragma unroll
                for (int u = 0; u < 8; ++u) {
                    tile[(wrow0 + li[u]) * 65 + lane] += v[u] * ww[u];  // wave-exclusive
                }
            }
        }
    }
    __syncthreads();

    // epilogue: rows [n0, n0+64) -> out[b*N+n] + bias, coalesced over c
    const int n0 = blockIdx.x * 64;
    const int c  = t & 63;
    const int bq = t >> 6;                      // 0..3
    const int n = n0 + c;
    if (n < N) {
        const float bv = bias[n];
        for (int b = bq; b < BATCH; b += 4)
            out[(size_t)b * N + n] = tile[c * 65 + b] + bv;
    }
}

// ---- fallback path (ws too small or N doesn't fit): direct atomics ----
__global__ void k_edge_scatter_direct(const float* __restrict__ in,
                                      const float* __restrict__ W3,
                                      const float* __restrict__ velocity,
                                      const int* __restrict__ I,
                                      const int* __restrict__ J,
                                      float* __restrict__ out, int N, int E) {
    const int lane = threadIdx.x & 63;
    const long wave   = (long)blockIdx.x * (blockDim.x >> 6) + (threadIdx.x >> 6);
    const long nwaves = (long)gridDim.x * (blockDim.x >> 6);
    for (long base = wave * 64; base < E; base += nwaves * 64) {
        const long e = base + lane;
        int iv = 0, jv = 0; float wvv = 0.f;
        if (e < E) { iv = I[e]; jv = J[e]; wvv = W3[e] * velocity[jv]; }
        const int cnt = (int)((E - base) < 64 ? (E - base) : 64);
        for (int k = 0; k < cnt; ++k) {
            const int   ii = __shfl(iv, k);
            const int   jj = __shfl(jv, k);
            const float wvx = __shfl(wvv, k);
            const float val = in[(size_t)lane * N + jj] * wvx;
            atomicAdd(&out[(size_t)lane * N + ii], val);
        }
    }
}

__global__ void k_add_bias(const float* __restrict__ bias, float* __restrict__ out, int N, int total) {
    int idx = blockIdx.x * blockDim.x + threadIdx.x;
    if (idx < total) out[idx] += bias[idx % N];
}

extern "C" void kernel_launch(void* const* d_in, const int* in_sizes, int n_in,
                              void* d_out, int out_size, void* d_ws, size_t ws_size,
                              hipStream_t stream) {
    const float* inputs   = (const float*)d_in[0];
    const float* W3       = (const float*)d_in[1];
    const float* bias     = (const float*)d_in[2];
    const float* velocity = (const float*)d_in[3];
    const int*   I        = (const int*)d_in[4];
    const int*   J        = (const int*)d_in[5];
    const int E = in_sizes[1];
    const int N = in_sizes[3];
    float* out = (float*)d_out;

    const size_t mat_elems = (size_t)N * BATCH;
    const int nseg = (N + SEG_ROWS - 1) / SEG_ROWS;  // 16-row segments
    const int nb_n = (N + 63) / 64;                  // transpose/gather blocks
    const int nb_e = (E + PCHUNK - 1) / PCHUNK;      // partition blocks
    const int nb_g = (nseg + 3) / 4;
    const int echunk = (E + nb_n - 1) / nb_n;        // edges histogrammed per prep block

    // ws: in_T | part | fine_hist | seg_base | gcursor
    const size_t need = mat_elems * sizeof(float)
                      + (size_t)E * sizeof(ull)
                      + (size_t)(nseg + (nseg + 1) + nseg) * sizeof(int);

    if (ws_size >= need && N <= 65535 && nseg <= MAX_NSEG) {
        float* in_T      = (float*)d_ws;
        ull*   part      = (ull*)(in_T + mat_elems);
        int*   fine_hist = (int*)(part + E);
        int*   seg_base  = fine_hist + nseg;
        int*   gcursor   = seg_base + nseg + 1;

        // stream-ordered zero BEFORE k_prep (same-dispatch zeroing raced in R7)
        hipMemsetAsync(fine_hist, 0, (size_t)nseg * sizeof(int), stream);
        k_prep     <<<nb_n, 256,  0, stream>>>(inputs, in_T, I, fine_hist, N, E, echunk);
        k_scan     <<<1,    1024, 0, stream>>>(fine_hist, seg_base, gcursor, nseg);
        k_partition<<<nb_e, 256,  0, stream>>>(I, J, W3, velocity, gcursor, part, nseg, E);
        k_gather   <<<nb_g, 256,  0, stream>>>(in_T, part, seg_base, bias, out, nseg, N);
    } else {
        hipMemsetAsync(out, 0, (size_t)out_size * sizeof(float), stream);
        const int waves_needed   = (E + 63) / 64;
        const int scatter_blocks = (waves_needed + 3) / 4;
        k_edge_scatter_direct<<<scatter_blocks, 256, 0, stream>>>(inputs, W3, velocity, I, J, out, N, E);
        k_add_bias<<<(out_size + 255) / 256, 256, 0, stream>>>(bias, out, N, out_size);
    }
}

// Round 10
// 197.033 us; speedup vs baseline: 2.5100x; 1.3369x over previous
//
#include <hip/hip_runtime.h>

// out[b, I[e]] += inputs[b, J[e]] * W3[e] * velocity[J[e]]; out += bias
// R2: per-edge global atomics = 204.8MB atomic-path traffic (bound).
// R4: bucket build -> WRITE 47MB = 1 line per scattered 8B record.
// R5: nt stores FALSIFIED (nt = no-allocate => partial-line fabric writes).
// R6: 2-pass counting sort, dense writes -> 157.1us (best so far).
// R7: same-dispatch hist zero -> RACE -> tripwire.
// R8: 196-block gather + LDS atomics -> 382us (starved grid, LDS-atomic serial).
// R9: per-edge GLOBAL hist atomics onto 196 lines -> k_prep 79us, WRITE +23MB:
//     concentrated global atomics are ~25x costlier than spread ones.
// R10: ATOMIC-FREE build. Counting-sort offsets via dense per-chunk LDS
//     histograms + 2D exclusive scan (chunk_hist[b][s] -> running col sums).
//     Partition reads its precomputed base row; only LDS atomics for ranks.
//     No global atomics, no memsets in fast path. Gather = R9 (wave-exclusive
//     16-row segs, 782 blocks, 8-wide ILP, plain LDS RMW).

#define BATCH 64
#define SEG_ROWS 16           // rows per segment (= per gather wave)
#define MAX_NSEG 4096         // static LDS sizing
#define PCHUNK 16384          // edges per hist/partition block

typedef unsigned long long ull;

// ---- K1: transpose inputs [B,N] -> in_T [N,B] ----
__global__ void k_prep(const float* __restrict__ in, float* __restrict__ in_T, int N) {
    const int t = threadIdx.x;
    __shared__ float tile[64 * 65];
    const int n0 = blockIdx.x * 64;
    const int x  = t & 63;
    const int r  = t >> 6;
    for (int b = r; b < BATCH; b += 4) {
        float v = 0.f;
        if (n0 + x < N) v = in[(size_t)b * N + n0 + x];
        tile[x * 65 + b] = v;
    }
    __syncthreads();
    for (int xr = r; xr < 64; xr += 4) {
        if (n0 + xr < N) in_T[(size_t)(n0 + xr) * BATCH + x] = tile[xr * 65 + x];
    }
}

// ---- K2: per-chunk LDS histogram -> dense chunk_hist[b][s] (no global atomics)
__global__ void k_hist(const int* __restrict__ I, int* __restrict__ chunk_hist,
                       int nseg, int E) {
    __shared__ int h[MAX_NSEG];
    const int t = threadIdx.x;
    for (int s = t; s < nseg; s += 256) h[s] = 0;
    __syncthreads();
    const int e0 = blockIdx.x * PCHUNK;
    int e1 = e0 + PCHUNK; if (e1 > E) e1 = E;
    for (int e = e0 + t; e < e1; e += 256) atomicAdd(&h[I[e] >> 4], 1);
    __syncthreads();
    int* row = chunk_hist + (size_t)blockIdx.x * nseg;
    for (int s = t; s < nseg; s += 256) row[s] = h[s];   // dense, coalesced
}

// ---- K3: column-wise exclusive scan over chunks (in place); emit col totals
__global__ void k_colscan(int* __restrict__ chunk_hist, int* __restrict__ col_tot,
                          int nseg, int nchunk) {
    const int s = blockIdx.x * 256 + threadIdx.x;
    if (s >= nseg) return;
    int run = 0;
    for (int b = 0; b < nchunk; ++b) {
        const size_t idx = (size_t)b * nseg + s;
        const int v = chunk_hist[idx];
        chunk_hist[idx] = run;                           // exclusive over chunks
        run += v;
    }
    col_tot[s] = run;
}

// ---- K4: exclusive scan of nseg (<=4096) totals -> seg_base ----
__global__ void __launch_bounds__(1024) k_scan(
        const int* __restrict__ col_tot, int* __restrict__ seg_base, int nseg) {
    __shared__ int sums[1024];
    const int t = threadIdx.x;
    const int i0 = t * 4;
    int v0 = (i0 + 0 < nseg) ? col_tot[i0 + 0] : 0;
    int v1 = (i0 + 1 < nseg) ? col_tot[i0 + 1] : 0;
    int v2 = (i0 + 2 < nseg) ? col_tot[i0 + 2] : 0;
    int v3 = (i0 + 3 < nseg) ? col_tot[i0 + 3] : 0;
    const int s = v0 + v1 + v2 + v3;
    sums[t] = s;
    __syncthreads();
    for (int off = 1; off < 1024; off <<= 1) {
        const int u = (t >= off) ? sums[t - off] : 0;
        __syncthreads();
        sums[t] += u;
        __syncthreads();
    }
    int run = sums[t] - s;                       // exclusive prefix
    if (i0 + 0 < nseg) { seg_base[i0 + 0] = run; run += v0; }
    if (i0 + 1 < nseg) { seg_base[i0 + 1] = run; run += v1; }
    if (i0 + 2 < nseg) { seg_base[i0 + 2] = run; run += v2; }
    if (i0 + 3 < nseg) { seg_base[i0 + 3] = run; run += v3; }
    if (t == 1023) seg_base[nseg] = sums[1023];  // = E
}

// ---- K5: partition into 16-row segments. Base = seg_base + chunk offset
// (precomputed, NO global atomics); ranks via LDS atomics only.
// record u64: hi32 = bits(w), lo32 = (i & 15) << 16 | j
__global__ void __launch_bounds__(512) k_partition(
        const int* __restrict__ I, const int* __restrict__ J,
        const float* __restrict__ W3, const float* __restrict__ velocity,
        const int* __restrict__ chunk_hist, const int* __restrict__ seg_base,
        ull* __restrict__ part, int nseg, int E) {
    __shared__ int base[MAX_NSEG];
    __shared__ int rank[MAX_NSEG];
    const int t = threadIdx.x;
    const int* row = chunk_hist + (size_t)blockIdx.x * nseg;
    for (int s = t; s < nseg; s += 512) {
        base[s] = seg_base[s] + row[s];
        rank[s] = 0;
    }
    __syncthreads();
    const int e0 = blockIdx.x * PCHUNK;
    int e1 = e0 + PCHUNK; if (e1 > E) e1 = E;
    for (int e = e0 + t; e < e1; e += 512) {
        const int   i = I[e];
        const int   j = J[e];
        const float w = W3[e] * velocity[j];
        const int   s = i >> 4;
        const int   r = atomicAdd(&rank[s], 1);          // LDS atomic
        const unsigned lo = ((unsigned)(i & 15) << 16) | (unsigned)j;
        part[(size_t)base[s] + r] = ((ull)__float_as_uint(w) << 32) | lo;
    }
}

// ---- K6: gather. Block = 4 waves; wave = one 16-row segment (exclusive).
// 8-wide batched shfl->load, plain LDS RMW, fused bias + transposed store. ----
__global__ void __launch_bounds__(256) k_gather(
        const float* __restrict__ in_T, const ull* __restrict__ part,
        const int* __restrict__ seg_base, const float* __restrict__ bias,
        float* __restrict__ out, int nseg, int N) {
    __shared__ float tile[64 * 65];             // 64 rows = 4 waves x 16
    const int t    = threadIdx.x;
    const int lane = t & 63;
    const int w    = t >> 6;                    // wave 0..3
    const int seg  = blockIdx.x * 4 + w;

    for (int idx = t; idx < 64 * 65; idx += 256) tile[idx] = 0.f;
    __syncthreads();

    if (seg < nseg) {
        const int wrow0 = w * 16;               // this wave's first local row
        const int beg = seg_base[seg];
        const int end = seg_base[seg + 1];

        for (int base = beg; base < end; base += 64) {
            int cc = end - base; if (cc > 64) cc = 64;
            ull rec = 0ull;                     // pad -> adds 0 to wave's row0
            if (lane < cc) rec = part[base + lane];
            const int rlo = (int)(unsigned)(rec & 0xffffffffu);
            const int rhi = (int)(unsigned)(rec >> 32);
            for (int k0 = 0; k0 < cc; k0 += 8) {
                float v[8], ww[8]; int li[8];
                #pragma unroll
                for (int u = 0; u < 8; ++u) {
                    const int k = k0 + u;
                    const unsigned ij = (unsigned)__shfl(rlo, k);
                    ww[u] = __uint_as_float((unsigned)__shfl(rhi, k));
                    li[u] = (int)((ij >> 16) & 15);   // row within segment
                    const int j = (int)(ij & 0xffffu);
                    v[u] = in_T[j * BATCH + lane];    // 8 independent loads in flight
                }
                #pragma unroll
                for (int u = 0; u < 8; ++u) {
                    tile[(wrow0 + li[u]) * 65 + lane] += v[u] * ww[u];  // wave-exclusive
                }
            }
        }
    }
    __syncthreads();

    // epilogue: rows [n0, n0+64) -> out[b*N+n] + bias, coalesced over c
    const int n0 = blockIdx.x * 64;
    const int c  = t & 63;
    const int bq = t >> 6;                      // 0..3
    const int n = n0 + c;
    if (n < N) {
        const float bv = bias[n];
        for (int b = bq; b < BATCH; b += 4)
            out[(size_t)b * N + n] = tile[c * 65 + b] + bv;
    }
}

// ---- fallback path (ws too small or N doesn't fit): direct atomics ----
__global__ void k_edge_scatter_direct(const float* __restrict__ in,
                                      const float* __restrict__ W3,
                                      const float* __restrict__ velocity,
                                      const int* __restrict__ I,
                                      const int* __restrict__ J,
                                      float* __restrict__ out, int N, int E) {
    const int lane = threadIdx.x & 63;
    const long wave   = (long)blockIdx.x * (blockDim.x >> 6) + (threadIdx.x >> 6);
    const long nwaves = (long)gridDim.x * (blockDim.x >> 6);
    for (long base = wave * 64; base < E; base += nwaves * 64) {
        const long e = base + lane;
        int iv = 0, jv = 0; float wvv = 0.f;
        if (e < E) { iv = I[e]; jv = J[e]; wvv = W3[e] * velocity[jv]; }
        const int cnt = (int)((E - base) < 64 ? (E - base) : 64);
        for (int k = 0; k < cnt; ++k) {
            const int   ii = __shfl(iv, k);
            const int   jj = __shfl(jv, k);
            const float wvx = __shfl(wvv, k);
            const float val = in[(size_t)lane * N + jj] * wvx;
            atomicAdd(&out[(size_t)lane * N + ii], val);
        }
    }
}

__global__ void k_add_bias(const float* __restrict__ bias, float* __restrict__ out, int N, int total) {
    int idx = blockIdx.x * blockDim.x + threadIdx.x;
    if (idx < total) out[idx] += bias[idx % N];
}

extern "C" void kernel_launch(void* const* d_in, const int* in_sizes, int n_in,
                              void* d_out, int out_size, void* d_ws, size_t ws_size,
                              hipStream_t stream) {
    const float* inputs   = (const float*)d_in[0];
    const float* W3       = (const float*)d_in[1];
    const float* bias     = (const float*)d_in[2];
    const float* velocity = (const float*)d_in[3];
    const int*   I        = (const int*)d_in[4];
    const int*   J        = (const int*)d_in[5];
    const int E = in_sizes[1];
    const int N = in_sizes[3];
    float* out = (float*)d_out;

    const size_t mat_elems = (size_t)N * BATCH;
    const int nseg   = (N + SEG_ROWS - 1) / SEG_ROWS;  // 16-row segments
    const int nb_n   = (N + 63) / 64;                  // transpose blocks
    const int nchunk = (E + PCHUNK - 1) / PCHUNK;      // hist/partition blocks
    const int nb_g   = (nseg + 3) / 4;                 // gather blocks
    const int nb_c   = (nseg + 255) / 256;             // colscan blocks

    // ws: in_T | part | chunk_hist[nchunk][nseg] | col_tot | seg_base
    const size_t need = mat_elems * sizeof(float)
                      + (size_t)E * sizeof(ull)
                      + ((size_t)nchunk * nseg + nseg + (nseg + 1)) * sizeof(int);

    if (ws_size >= need && N <= 65535 && nseg <= MAX_NSEG) {
        float* in_T       = (float*)d_ws;
        ull*   part       = (ull*)(in_T + mat_elems);
        int*   chunk_hist = (int*)(part + E);
        int*   col_tot    = chunk_hist + (size_t)nchunk * nseg;
        int*   seg_base   = col_tot + nseg;

        k_prep     <<<nb_n,   256,  0, stream>>>(inputs, in_T, N);
        k_hist     <<<nchunk, 256,  0, stream>>>(I, chunk_hist, nseg, E);
        k_colscan  <<<nb_c,   256,  0, stream>>>(chunk_hist, col_tot, nseg, nchunk);
        k_scan     <<<1,      1024, 0, stream>>>(col_tot, seg_base, nseg);
        k_partition<<<nchunk, 512,  0, stream>>>(I, J, W3, velocity, chunk_hist,
                                                 seg_base, part, nseg, E);
        k_gather   <<<nb_g,   256,  0, stream>>>(in_T, part, seg_base, bias, out, nseg, N);
    } else {
        hipMemsetAsync(out, 0, (size_t)out_size * sizeof(float), stream);
        const int waves_needed   = (E + 63) / 64;
        const int scatter_blocks = (waves_needed + 3) / 4;
        k_edge_scatter_direct<<<scatter_blocks, 256, 0, stream>>>(inputs, W3, velocity, I, J, out, N, E);
        k_add_bias<<<(out_size + 255) / 256, 256, 0, stream>>>(bias, out, N, out_size);
    }
}

// Round 11
// 180.940 us; speedup vs baseline: 2.7332x; 1.0889x over previous
//
#include <hip/hip_runtime.h>

// out[b, I[e]] += inputs[b, J[e]] * W3[e] * velocity[J[e]]; out += bias
// R2: per-edge global atomics = 204.8MB atomic-path traffic (bound).
// R4: bucket build -> WRITE 47MB = 1 line per scattered 8B record.
// R5: nt stores FALSIFIED (nt = no-allocate => partial-line fabric writes).
// R6: 2-pass counting sort, dense writes -> 157.1us (prev best).
// R7: same-dispatch hist zero -> RACE -> tripwire.
// R8: 196-block gather + LDS atomics -> 382us (starved grid).
// R9: concentrated global hist atomics -> 79us prep (~25x cost of spread).
// R10: atomic-free build (LDS hists + 2D scan) -> 197us; partition 51us at
//      OCCUPANCY 3.2% (49 blocks = 392 waves on 8192 slots: grid starvation).
// R11: re-balance grids. chunk 2048 -> 391 hist/partition blocks (38% slots);
//      partition base+rank merged into one LDS array (atomicAdd returns pos);
//      gather = 128-thr blocks (2 waves/2 segs) -> 1563 blocks ~ 6/CU.

#define BATCH 64
#define SEG_ROWS 16           // rows per segment (= per gather wave)
#define MAX_NSEG 4096         // static LDS sizing
#define PCHUNK 2048           // edges per hist/partition block

typedef unsigned long long ull;

// ---- K1: transpose inputs [B,N] -> in_T [N,B] ----
__global__ void k_prep(const float* __restrict__ in, float* __restrict__ in_T, int N) {
    const int t = threadIdx.x;
    __shared__ float tile[64 * 65];
    const int n0 = blockIdx.x * 64;
    const int x  = t & 63;
    const int r  = t >> 6;
    for (int b = r; b < BATCH; b += 4) {
        float v = 0.f;
        if (n0 + x < N) v = in[(size_t)b * N + n0 + x];
        tile[x * 65 + b] = v;
    }
    __syncthreads();
    for (int xr = r; xr < 64; xr += 4) {
        if (n0 + xr < N) in_T[(size_t)(n0 + xr) * BATCH + x] = tile[xr * 65 + x];
    }
}

// ---- K2: per-chunk LDS histogram -> dense chunk_hist[b][s] (no global atomics)
__global__ void k_hist(const int* __restrict__ I, int* __restrict__ chunk_hist,
                       int nseg, int E) {
    __shared__ int h[MAX_NSEG];
    const int t = threadIdx.x;
    for (int s = t; s < nseg; s += 256) h[s] = 0;
    __syncthreads();
    const int e0 = blockIdx.x * PCHUNK;
    int e1 = e0 + PCHUNK; if (e1 > E) e1 = E;
    for (int e = e0 + t; e < e1; e += 256) atomicAdd(&h[I[e] >> 4], 1);
    __syncthreads();
    int* row = chunk_hist + (size_t)blockIdx.x * nseg;
    for (int s = t; s < nseg; s += 256) row[s] = h[s];   // dense, coalesced
}

// ---- K3: column-wise exclusive scan over chunks (in place); emit col totals
__global__ void k_colscan(int* __restrict__ chunk_hist, int* __restrict__ col_tot,
                          int nseg, int nchunk) {
    const int s = blockIdx.x * 256 + threadIdx.x;
    if (s >= nseg) return;
    int run = 0;
    int b = 0;
    for (; b + 4 <= nchunk; b += 4) {            // unrolled: 4 loads in flight
        const size_t i0 = (size_t)(b + 0) * nseg + s;
        const size_t i1 = (size_t)(b + 1) * nseg + s;
        const size_t i2 = (size_t)(b + 2) * nseg + s;
        const size_t i3 = (size_t)(b + 3) * nseg + s;
        const int v0 = chunk_hist[i0];
        const int v1 = chunk_hist[i1];
        const int v2 = chunk_hist[i2];
        const int v3 = chunk_hist[i3];
        chunk_hist[i0] = run;
        chunk_hist[i1] = run + v0;
        chunk_hist[i2] = run + v0 + v1;
        chunk_hist[i3] = run + v0 + v1 + v2;
        run += v0 + v1 + v2 + v3;
    }
    for (; b < nchunk; ++b) {
        const size_t idx = (size_t)b * nseg + s;
        const int v = chunk_hist[idx];
        chunk_hist[idx] = run;
        run += v;
    }
    col_tot[s] = run;
}

// ---- K4: exclusive scan of nseg (<=4096) totals -> seg_base ----
__global__ void __launch_bounds__(1024) k_scan(
        const int* __restrict__ col_tot, int* __restrict__ seg_base, int nseg) {
    __shared__ int sums[1024];
    const int t = threadIdx.x;
    const int i0 = t * 4;
    int v0 = (i0 + 0 < nseg) ? col_tot[i0 + 0] : 0;
    int v1 = (i0 + 1 < nseg) ? col_tot[i0 + 1] : 0;
    int v2 = (i0 + 2 < nseg) ? col_tot[i0 + 2] : 0;
    int v3 = (i0 + 3 < nseg) ? col_tot[i0 + 3] : 0;
    const int s = v0 + v1 + v2 + v3;
    sums[t] = s;
    __syncthreads();
    for (int off = 1; off < 1024; off <<= 1) {
        const int u = (t >= off) ? sums[t - off] : 0;
        __syncthreads();
        sums[t] += u;
        __syncthreads();
    }
    int run = sums[t] - s;                       // exclusive prefix
    if (i0 + 0 < nseg) { seg_base[i0 + 0] = run; run += v0; }
    if (i0 + 1 < nseg) { seg_base[i0 + 1] = run; run += v1; }
    if (i0 + 2 < nseg) { seg_base[i0 + 2] = run; run += v2; }
    if (i0 + 3 < nseg) { seg_base[i0 + 3] = run; run += v3; }
    if (t == 1023) seg_base[nseg] = sums[1023];  // = E
}

// ---- K5: partition into 16-row segments. base[s] = seg_base[s] + chunk
// offset (precomputed, NO global atomics); atomicAdd(&base[s],1) IS the
// position (merged base+rank: half the LDS, no extra zero pass).
// record u64: hi32 = bits(w), lo32 = (i & 15) << 16 | j
__global__ void __launch_bounds__(512) k_partition(
        const int* __restrict__ I, const int* __restrict__ J,
        const float* __restrict__ W3, const float* __restrict__ velocity,
        const int* __restrict__ chunk_hist, const int* __restrict__ seg_base,
        ull* __restrict__ part, int nseg, int E) {
    __shared__ int base[MAX_NSEG];
    const int t = threadIdx.x;
    const int* row = chunk_hist + (size_t)blockIdx.x * nseg;
    for (int s = t; s < nseg; s += 512) base[s] = seg_base[s] + row[s];
    __syncthreads();
    const int e0 = blockIdx.x * PCHUNK;
    int e1 = e0 + PCHUNK; if (e1 > E) e1 = E;
    for (int e = e0 + t; e < e1; e += 512) {
        const int   i = I[e];
        const int   j = J[e];
        const float w = W3[e] * velocity[j];
        const int   s = i >> 4;
        const int   pos = atomicAdd(&base[s], 1);        // LDS atomic -> position
        const unsigned lo = ((unsigned)(i & 15) << 16) | (unsigned)j;
        part[(size_t)pos] = ((ull)__float_as_uint(w) << 32) | lo;
    }
}

// ---- K6: gather. Block = 2 waves; wave = one 16-row segment (exclusive).
// 8-wide batched shfl->load, plain LDS RMW, fused bias + transposed store.
// 1563 blocks ~ 6/CU for even packing. ----
__global__ void __launch_bounds__(128) k_gather(
        const float* __restrict__ in_T, const ull* __restrict__ part,
        const int* __restrict__ seg_base, const float* __restrict__ bias,
        float* __restrict__ out, int nseg, int N) {
    __shared__ float tile[32 * 65];             // 32 rows = 2 waves x 16
    const int t    = threadIdx.x;
    const int lane = t & 63;
    const int w    = t >> 6;                    // wave 0..1
    const int seg  = blockIdx.x * 2 + w;

    for (int idx = t; idx < 32 * 65; idx += 128) tile[idx] = 0.f;
    __syncthreads();

    if (seg < nseg) {
        const int wrow0 = w * 16;               // this wave's first local row
        const int beg = seg_base[seg];
        const int end = seg_base[seg + 1];

        for (int base = beg; base < end; base += 64) {
            int cc = end - base; if (cc > 64) cc = 64;
            ull rec = 0ull;                     // pad -> adds 0 to wave's row0
            if (lane < cc) rec = part[base + lane];
            const int rlo = (int)(unsigned)(rec & 0xffffffffu);
            const int rhi = (int)(unsigned)(rec >> 32);
            for (int k0 = 0; k0 < cc; k0 += 8) {
                float v[8], ww[8]; int li[8];
                #pragma unroll
                for (int u = 0; u < 8; ++u) {
                    const int k = k0 + u;
                    const unsigned ij = (unsigned)__shfl(rlo, k);
                    ww[u] = __uint_as_float((unsigned)__shfl(rhi, k));
                    li[u] = (int)((ij >> 16) & 15);   // row within segment
                    const int j = (int)(ij & 0xffffu);
                    v[u] = in_T[j * BATCH + lane];    // 8 independent loads in flight
                }
                #pragma unroll
                for (int u = 0; u < 8; ++u) {
                    tile[(wrow0 + li[u]) * 65 + lane] += v[u] * ww[u];  // wave-exclusive
                }
            }
        }
    }
    __syncthreads();

    // epilogue: rows [n0, n0+32) -> out[b*N+n] + bias, coalesced over c
    const int n0 = blockIdx.x * 32;
    const int c  = t & 31;
    const int bq = t >> 5;                      // 0..3
    const int n = n0 + c;
    if (n < N) {
        const float bv = bias[n];
        for (int b = bq; b < BATCH; b += 4)
            out[(size_t)b * N + n] = tile[c * 65 + b] + bv;
    }
}

// ---- fallback path (ws too small or N doesn't fit): direct atomics ----
__global__ void k_edge_scatter_direct(const float* __restrict__ in,
                                      const float* __restrict__ W3,
                                      const float* __restrict__ velocity,
                                      const int* __restrict__ I,
                                      const int* __restrict__ J,
                                      float* __restrict__ out, int N, int E) {
    const int lane = threadIdx.x & 63;
    const long wave   = (long)blockIdx.x * (blockDim.x >> 6) + (threadIdx.x >> 6);
    const long nwaves = (long)gridDim.x * (blockDim.x >> 6);
    for (long base = wave * 64; base < E; base += nwaves * 64) {
        const long e = base + lane;
        int iv = 0, jv = 0; float wvv = 0.f;
        if (e < E) { iv = I[e]; jv = J[e]; wvv = W3[e] * velocity[jv]; }
        const int cnt = (int)((E - base) < 64 ? (E - base) : 64);
        for (int k = 0; k < cnt; ++k) {
            const int   ii = __shfl(iv, k);
            const int   jj = __shfl(jv, k);
            const float wvx = __shfl(wvv, k);
            const float val = in[(size_t)lane * N + jj] * wvx;
            atomicAdd(&out[(size_t)lane * N + ii], val);
        }
    }
}

__global__ void k_add_bias(const float* __restrict__ bias, float* __restrict__ out, int N, int total) {
    int idx = blockIdx.x * blockDim.x + threadIdx.x;
    if (idx < total) out[idx] += bias[idx % N];
}

extern "C" void kernel_launch(void* const* d_in, const int* in_sizes, int n_in,
                              void* d_out, int out_size, void* d_ws, size_t ws_size,
                              hipStream_t stream) {
    const float* inputs   = (const float*)d_in[0];
    const float* W3       = (const float*)d_in[1];
    const float* bias     = (const float*)d_in[2];
    const float* velocity = (const float*)d_in[3];
    const int*   I        = (const int*)d_in[4];
    const int*   J        = (const int*)d_in[5];
    const int E = in_sizes[1];
    const int N = in_sizes[3];
    float* out = (float*)d_out;

    const size_t mat_elems = (size_t)N * BATCH;
    const int nseg   = (N + SEG_ROWS - 1) / SEG_ROWS;  // 16-row segments
    const int nb_n   = (N + 63) / 64;                  // transpose blocks
    const int nchunk = (E + PCHUNK - 1) / PCHUNK;      // hist/partition blocks
    const int nb_g   = (nseg + 1) / 2;                 // gather blocks (2 segs each)
    const int nb_c   = (nseg + 255) / 256;             // colscan blocks

    // ws: in_T | part | chunk_hist[nchunk][nseg] | col_tot | seg_base
    const size_t need = mat_elems * sizeof(float)
                      + (size_t)E * sizeof(ull)
                      + ((size_t)nchunk * nseg + nseg + (nseg + 1)) * sizeof(int);

    if (ws_size >= need && N <= 65535 && nseg <= MAX_NSEG) {
        float* in_T       = (float*)d_ws;
        ull*   part       = (ull*)(in_T + mat_elems);
        int*   chunk_hist = (int*)(part + E);
        int*   col_tot    = chunk_hist + (size_t)nchunk * nseg;
        int*   seg_base   = col_tot + nseg;

        k_prep     <<<nb_n,   256,  0, stream>>>(inputs, in_T, N);
        k_hist     <<<nchunk, 256,  0, stream>>>(I, chunk_hist, nseg, E);
        k_colscan  <<<nb_c,   256,  0, stream>>>(chunk_hist, col_tot, nseg, nchunk);
        k_scan     <<<1,      1024, 0, stream>>>(col_tot, seg_base, nseg);
        k_partition<<<nchunk, 512,  0, stream>>>(I, J, W3, velocity, chunk_hist,
                                                 seg_base, part, nseg, E);
        k_gather   <<<nb_g,   128,  0, stream>>>(in_T, part, seg_base, bias, out, nseg, N);
    } else {
        hipMemsetAsync(out, 0, (size_t)out_size * sizeof(float), stream);
        const int waves_needed   = (E + 63) / 64;
        const int scatter_blocks = (waves_needed + 3) / 4;
        k_edge_scatter_direct<<<scatter_blocks, 256, 0, stream>>>(inputs, W3, velocity, I, J, out, N, E);
        k_add_bias<<<(out_size + 255) / 256, 256, 0, stream>>>(bias, out, N, out_size);
    }
}